// Round 23
// baseline (147.298 us; speedup 1.0000x reference)
//
#include <hip/hip_runtime.h>
#include <cstdint>

#define B_ 2
#define S_ 2048
#define D_ 1024
#define H_ 16
#define DK_ 64
// 0.125 (1/sqrt(DK)) * log2(e): folded into Wq/bq so softmax uses exp2 directly
#define SCALE_ 0.18033688011112042f

typedef float f32x4 __attribute__((ext_vector_type(4)));
typedef float f32x16 __attribute__((ext_vector_type(16)));
typedef __bf16 bf16x8 __attribute__((ext_vector_type(8)));
typedef unsigned short u16x8 __attribute__((ext_vector_type(8)));
typedef unsigned short u16x4 __attribute__((ext_vector_type(4)));
typedef unsigned int u32x4 __attribute__((ext_vector_type(4)));

__device__ __forceinline__ unsigned short f2bf(float x) {
  unsigned int u = __builtin_bit_cast(unsigned int, x);
  u += 0x7FFFu + ((u >> 16) & 1u);   // round-to-nearest-even
  return (unsigned short)(u >> 16);
}

__device__ __forceinline__ void gload16(const void* g, void* l) {
  __builtin_amdgcn_global_load_lds((__attribute__((address_space(1))) void*)(void*)g,
                                   (__attribute__((address_space(3))) void*)l, 16, 0, 0);
}

__device__ __forceinline__ float exp2v(float x) {
  float r;
  asm("v_exp_f32 %0, %1" : "=v"(r) : "v"(x));
  return r;
}

__device__ __forceinline__ unsigned int cvtpk(float a, float b) {
  unsigned int r;
  asm("v_cvt_pk_bf16_f32 %0, %1, %2" : "=v"(r) : "v"(a), "v"(b));
  return r;
}

// sign-extended 1-bit field: 0 or 0xFFFFFFFF
__device__ __forceinline__ unsigned int bit_mask(unsigned int w, int bit) {
#if __has_builtin(__builtin_amdgcn_sbfe)
  return (unsigned int)__builtin_amdgcn_sbfe((int)w, bit, 1);
#else
  return (unsigned int)((int)(w << (31 - bit)) >> 31);
#endif
}

// ---------------- prep: cvt3 | wtrans | maskpack ----------------
// blocks [0,6144): fp32->bf16 convert of q/k/v (2048 blocks each)
// blocks [6144,10240): weight transpose+convert
// blocks [10240,18432): mask bit-pack (1024 elements per block, batched ballots)
__global__ __launch_bounds__(256) void prep_kernel(
    const float* __restrict__ q, const float* __restrict__ k, const float* __restrict__ v,
    unsigned short* __restrict__ oq, unsigned short* __restrict__ ok,
    unsigned short* __restrict__ ov,
    const float* __restrict__ w0, const float* __restrict__ w1,
    const float* __restrict__ w2, const float* __restrict__ w3,
    unsigned short* o0, unsigned short* o1, unsigned short* o2, unsigned short* o3,
    const int* __restrict__ mask, unsigned int* __restrict__ mb) {
  __shared__ float t[32][33];
  const int bid = blockIdx.x;
  const int tid = threadIdx.x;
  if (bid < 6144) {
    const int z = bid >> 11, vb = bid & 2047;
    const float* in = z == 0 ? q : z == 1 ? k : v;
    unsigned short* out = z == 0 ? oq : z == 1 ? ok : ov;
    const int n = B_ * S_ * D_;
    int idx = vb * 256 + tid;
#pragma unroll
    for (int i = idx * 4; i < n; i += 2048 * 256 * 4) {
      f32x4 vv = *(const f32x4*)(in + i);
      u16x4 o;
#pragma unroll
      for (int j = 0; j < 4; ++j) o[j] = f2bf(vv[j]);
      *(u16x4*)(out + i) = o;
    }
  } else if (bid < 10240) {
    const int r = bid - 6144;
    const int z = r >> 10, rr = r & 1023;
    const float* W;
    unsigned short* O;
    float sc = 1.f;
    if (z == 0) { W = w0; O = o0; sc = SCALE_; }
    else if (z == 1) { W = w1; O = o1; }
    else if (z == 2) { W = w2; O = o2; }
    else { W = w3; O = o3; }
    const int n0 = (rr & 31) * 32, k0 = (rr >> 5) * 32;
    const int tx = tid & 31, ty = tid >> 5;
    for (int i = ty; i < 32; i += 8) t[i][tx] = W[(size_t)(k0 + i) * D_ + n0 + tx];
    __syncthreads();
    for (int i = ty; i < 32; i += 8) O[(size_t)(n0 + i) * D_ + k0 + tx] = f2bf(t[tx][i] * sc);
  } else {
    const int blk = bid - 10240;           // 0..8191
    const int w = tid >> 6, lane = tid & 63;
    const size_t base = ((size_t)blk * 4 + w) * 256;  // element base for this wave
    const int* mp = mask + base;
    // strided loads keep ballot bit order == element order within each 64-group
    unsigned long long b0 = __ballot(mp[lane] != 0);
    unsigned long long b1 = __ballot(mp[64 + lane] != 0);
    unsigned long long b2 = __ballot(mp[128 + lane] != 0);
    unsigned long long b3 = __ballot(mp[192 + lane] != 0);
    if (lane == 0) {
      unsigned long long* dst = (unsigned long long*)(mb + (base >> 5));
      dst[0] = b0; dst[1] = b1; dst[2] = b2; dst[3] = b3;
    }
  }
}

// ---------------- TMxTN bf16 GEMM, B transposed (BT[n][k]), bias add ----------------
// MODE: 0 = bf16 row-major out, 1 = f32 row-major out, 2 = bf16 transposed out to [B][D][S]
// gload_lds both operands; 3-buffer LDS, staged 2 tiles ahead, counted-vmcnt barriers
// (stage = TM/64 + TN/64 loads; vmcnt(SLOADS) at barrier retires stage(kt+1) while
// stage(kt+2) crosses in flight with ~2 iterations of latency cover). R20-proven.
template <int MODE, int TM, int TN, int NWM, int NWN>
__device__ __forceinline__ void gemm_t(const unsigned short* __restrict__ A16,
                                       const unsigned short* __restrict__ BT,
                                       const float* __restrict__ bias, float bsc,
                                       void* __restrict__ Cp,
                                       unsigned short* __restrict__ AlS,
                                       unsigned short* __restrict__ BlS,
                                       int M, int N, int K) {
  static_assert(NWM * NWN == 4, "4 waves");
  constexpr int WM = TM / NWM;    // rows per wave
  constexpr int WN = TN / NWN;    // cols per wave
  constexpr int MR = WM / 16, NR = WN / 16;
  constexpr int ASTRIDE = TM * 32;
  constexpr int BSTRIDE = TN * 32;
  const int tid = threadIdx.x;
  const int lane = tid & 63;
  const int w = tid >> 6;
  const int wr = w / NWN, wc = w % NWN;
  // XCD-chunked bijective remap (nwg must be a multiple of 8)
  const int nwg = gridDim.x * gridDim.y;
  const int wg = blockIdx.x + gridDim.x * blockIdx.y;
  const int work = (wg & 7) * (nwg >> 3) + (wg >> 3);
  const int nx = N / TN;
  const int m0 = (work / nx) * TM, n0 = (work % nx) * TN;

  f32x4 acc[MR][NR] = {};
  const int nk = K / 32;
  const int srow = lane >> 2;                              // staging row within 16-row chunk
  const int sxor = ((lane & 3) ^ ((srow >> 1) & 3)) * 8;   // swizzled seg (ushort offset)

  const int fr = lane & 15;
  const int rsw = ((lane >> 4) ^ ((fr >> 1) & 3)) * 8;     // read seg (swizzled), ushorts

  auto stage = [&](int kt, int bufi) {
#pragma unroll
    for (int it = 0; it < TM / 64; ++it) {
      int chunk = it * 4 + w;
      gload16(A16 + (size_t)(m0 + chunk * 16 + srow) * K + kt * 32 + sxor,
              AlS + bufi * ASTRIDE + chunk * 512);
    }
#pragma unroll
    for (int it = 0; it < TN / 64; ++it) {
      int chunk = it * 4 + w;
      gload16(BT + (size_t)(n0 + chunk * 16 + srow) * K + kt * 32 + sxor,
              BlS + bufi * BSTRIDE + chunk * 512);
    }
  };
  auto compute = [&](int bufi) {
    bf16x8 af[MR], bf[NR];
#pragma unroll
    for (int i = 0; i < MR; ++i)
      af[i] = __builtin_bit_cast(bf16x8,
          *(const u16x8*)(AlS + bufi * ASTRIDE + (wr * WM + i * 16 + fr) * 32 + rsw));
#pragma unroll
    for (int j = 0; j < NR; ++j)
      bf[j] = __builtin_bit_cast(bf16x8,
          *(const u16x8*)(BlS + bufi * BSTRIDE + (wc * WN + j * 16 + fr) * 32 + rsw));
    __builtin_amdgcn_s_setprio(1);
#pragma unroll
    for (int i = 0; i < MR; ++i)
#pragma unroll
      for (int j = 0; j < NR; ++j)
        acc[i][j] = __builtin_amdgcn_mfma_f32_16x16x32_bf16(af[i], bf[j], acc[i][j], 0, 0, 0);
    __builtin_amdgcn_s_setprio(0);
  };

  constexpr int SLOADS = TM / 64 + TN / 64;
  stage(0, 0);
  if (nk > 1) stage(1, 1);
  asm volatile("s_waitcnt vmcnt(%0) lgkmcnt(0)" :: "i"(SLOADS) : "memory");  // stage0 done
  __builtin_amdgcn_s_barrier();
  __builtin_amdgcn_sched_barrier(0);
  for (int kt = 0; kt < nk; ++kt) {
    if (kt + 2 < nk) stage(kt + 2, (kt + 2) % 3);  // buffer last read at iter kt-1
    compute(kt % 3);
    if (kt + 1 < nk) {
      if (kt + 2 < nk)
        asm volatile("s_waitcnt vmcnt(%0) lgkmcnt(0)" :: "i"(SLOADS) : "memory");
      else
        asm volatile("s_waitcnt vmcnt(0) lgkmcnt(0)" ::: "memory");
      __builtin_amdgcn_s_barrier();
      __builtin_amdgcn_sched_barrier(0);
    }
  }

  const int rg = (lane >> 4) * 4;
  const int cg = lane & 15;
#pragma unroll
  for (int i = 0; i < MR; ++i)
#pragma unroll
    for (int j = 0; j < NR; ++j) {
      int col = n0 + wc * WN + j * 16 + cg;
      float bv = bias[col] * bsc;
#pragma unroll
      for (int e = 0; e < 4; ++e) {
        int row = m0 + wr * WM + i * 16 + rg + e;
        float v = acc[i][j][e] + bv;
        if (MODE == 1)
          ((float*)Cp)[(size_t)row * N + col] = v;
        else if (MODE == 0)
          ((unsigned short*)Cp)[(size_t)row * N + col] = f2bf(v);
        else
          ((unsigned short*)Cp)[((size_t)(row >> 11) * D_ + col) * S_ + (row & (S_ - 1))] = f2bf(v);
      }
    }
}

// qkv: bf16 inputs, 128x128 tiles (768 blocks, 3/CU all co-resident), 3-buffer 48KB LDS
__global__ __launch_bounds__(256) void qkv_gemm_kernel(
    const unsigned short* __restrict__ xq, const unsigned short* __restrict__ xk,
    const unsigned short* __restrict__ xv, const unsigned short* __restrict__ wtq,
    const unsigned short* __restrict__ wtk, const unsigned short* __restrict__ wtv,
    const float* __restrict__ bq, const float* __restrict__ bk, const float* __restrict__ bv,
    unsigned short* q, unsigned short* k, unsigned short* vt) {
  __shared__ alignas(16) unsigned short As[3 * 128 * 32];
  __shared__ alignas(16) unsigned short Bs[3 * 128 * 32];
  if (blockIdx.z == 0)
    gemm_t<0, 128, 128, 2, 2>(xq, wtq, bq, SCALE_, (void*)q, As, Bs, B_ * S_, D_, D_);
  else if (blockIdx.z == 1)
    gemm_t<0, 128, 128, 2, 2>(xk, wtk, bk, 1.f, (void*)k, As, Bs, B_ * S_, D_, D_);
  else
    gemm_t<2, 128, 128, 2, 2>(xv, wtv, bv, 1.f, (void*)vt, As, Bs, B_ * S_, D_, D_);
}

// out: 128x64 tiles, 3-buffer 2-ahead counted-vmcnt pipeline (R20-proven)
__global__ __launch_bounds__(256) void out_gemm_kernel(const unsigned short* __restrict__ x,
                                                       const unsigned short* __restrict__ wto,
                                                       const float* __restrict__ bo,
                                                       float* __restrict__ out) {
  __shared__ alignas(16) unsigned short As[3 * 128 * 32];
  __shared__ alignas(16) unsigned short Bs[3 * 64 * 32];
  gemm_t<1, 128, 64, 4, 1>(x, wto, bo, 1.f, (void*)out, As, Bs, B_ * S_, D_, D_);
}

// ---------------- flash attention, swapped-QK^T 32x32, clustered phases (R10 proven) ----------------
// Q,K bf16 [B,S,D] (Q pre-scaled by SCALE_); Vt bf16 [B,D,S]; mb bit-packed mask.
// 4 waves x 32 q-rows = 128 q/block; KVBLK=128 staged; double-buffered 64KB LDS;
// per iteration: [16 K ds_reads][stage][16 QK MFMA][16 V ds_reads][softmax][24 PV MFMA].
__global__ __launch_bounds__(256, 2) void attn_kernel(const unsigned short* __restrict__ Q,
                                                      const unsigned short* __restrict__ K,
                                                      const unsigned short* __restrict__ Vt,
                                                      const unsigned int* __restrict__ mb,
                                                      unsigned short* __restrict__ X) {
  __shared__ unsigned short Kl[2][128 * 64];     // [kv 0..127][d], XOR-swizzled 16B chunks
  __shared__ unsigned short Vl[2][2][64 * 64];   // [half][d][kv 64], XOR-swizzled

  const int tid = threadIdx.x;
  const int lane = tid & 63;
  const int w = tid >> 6;
  const int ql = lane & 31;
  const int hi = lane >> 5;

  // XCD-bijective remap: 512 blocks = 8 XCDs x 64; each XCD owns 4 consecutive bh
  const int wg = blockIdx.x + gridDim.x * blockIdx.y;
  const int swz = (wg & 7) * 64 + (wg >> 3);
  const int qt = swz & 15;
  const int bh = swz >> 4;
  const int b = bh >> 4, h = bh & 15;
  const int q_g = qt * 128 + w * 32 + ql;

  const size_t qkbase = ((size_t)b * S_) * D_ + h * DK_;
  const size_t vtbase = ((size_t)b * D_ + h * DK_) * S_;

  bf16x8 qf[4];
  {
    const unsigned short* qp = Q + qkbase + (size_t)q_g * D_ + hi * 8;
#pragma unroll
    for (int c = 0; c < 4; ++c)
      qf[c] = __builtin_bit_cast(bf16x8, *(const u16x8*)(qp + c * 16));
  }

  const int lr = lane >> 3;
  const int seg = (lane & 7) ^ lr;
  const unsigned short* Ks = K + qkbase + (size_t)(w * 32 + lr) * D_ + seg * 8;
  const unsigned short* Vs = Vt + vtbase + (size_t)(w * 16 + lr) * S_ + seg * 8;

  auto stage = [&](int kt, int bufi) {  // kt indexes 128-row KV tiles
#pragma unroll
    for (int c = 0; c < 4; ++c)
      gload16(Ks + ((size_t)kt * 128 + c * 8) * D_, &Kl[bufi][(w * 32 + c * 8) * 64]);
#pragma unroll
    for (int c = 0; c < 4; ++c)
      gload16(Vs + (size_t)((c & 1) * 8) * S_ + kt * 128 + (c >> 1) * 64,
              &Vl[bufi][c >> 1][(w * 16 + (c & 1) * 8) * 64]);
  };

  const unsigned long long* mrow =
      (const unsigned long long*)mb + ((size_t)b * S_ + q_g) * 32;

  f32x16 o0 = {}, o1 = {};  // O^T accumulators, d-tiles 0 (d 0..31) and 1 (d 32..63)
  f32x16 o2 = {};           // ones-MFMA accumulator: every row = sum_k P (lsum)
  const int sw = (ql & 7) << 4;

  const unsigned int one2 = 0x3F803F80u;  // two bf16 1.0
  const bf16x8 onesf = __builtin_bit_cast(bf16x8, u32x4{one2, one2, one2, one2});

  stage(0, 0);
  const int NT = S_ / 128;
  unsigned long long M0n = mrow[0], M1n = mrow[1];

  for (int kt = 0; kt < NT; ++kt) {
    const int buf = kt & 1;
    __syncthreads();                  // drains stage(kt); prior reads of buf^1 done
    unsigned long long M0 = M0n, M1 = M1n;

    // ---- phase 1: ALL K-fragment ds_reads (latency paid once, pipelined) ----
    bf16x8 kf[2][2][4];  // [half][subtile][c]
#pragma unroll
    for (int hh = 0; hh < 2; ++hh) {
      const char* Kb = (const char*)&Kl[buf][hh * 64 * 64];
#pragma unroll
      for (int r = 0; r < 2; ++r)
#pragma unroll
        for (int c = 0; c < 4; ++c)
          kf[hh][r][c] = __builtin_bit_cast(
              bf16x8, *(const u16x8*)(Kb + (((r * 32 + ql) * 128 + c * 32 + hi * 16) ^ sw)));
    }
    if (kt < NT - 1) {
      stage(kt + 1, buf ^ 1);
      M0n = mrow[kt * 2 + 2];  // prefetch next tile's mask words (off softmax path)
      M1n = mrow[kt * 2 + 3];
    }

    // ---- phase 2: QK^T MFMA cluster (16) ----
    f32x16 s[2][2] = {};  // [half][subtile]
    __builtin_amdgcn_s_setprio(1);
#pragma unroll
    for (int hh = 0; hh < 2; ++hh)
#pragma unroll
      for (int c = 0; c < 4; ++c) {
        s[hh][0] = __builtin_amdgcn_mfma_f32_32x32x16_bf16(kf[hh][0][c], qf[c], s[hh][0], 0, 0, 0);
        s[hh][1] = __builtin_amdgcn_mfma_f32_32x32x16_bf16(kf[hh][1][c], qf[c], s[hh][1], 0, 0, 0);
      }
    __builtin_amdgcn_s_setprio(0);

    // ---- phase 3: ALL V-fragment ds_reads (latency hides under softmax VALU) ----
    bf16x8 vf[2][2][4];  // [half][d-subtile][kc]
#pragma unroll
    for (int hh = 0; hh < 2; ++hh) {
      const char* Vb = (const char*)&Vl[buf][hh][0];
#pragma unroll
      for (int nt = 0; nt < 2; ++nt)
#pragma unroll
        for (int kc = 0; kc < 4; ++kc)
          vf[hh][nt][kc] = __builtin_bit_cast(
              bf16x8, *(const u16x8*)(Vb + (((nt * 32 + ql) * 128 + kc * 32 + hi * 16) ^ sw)));
    }

    // ---- phase 4: softmax + pack per half ----
    u32x4 pw[2][4];
#pragma unroll
    for (int hh = 0; hh < 2; ++hh) {
      const unsigned long long M = hh ? M1 : M0;
      unsigned int W0 = (unsigned int)(M >> (hi * 4));
      unsigned int W1 = (unsigned int)(M >> (32 + hi * 4));
#pragma unroll
      for (int r = 0; r < 16; ++r) {
        const int krl = (r & 3) + 8 * (r >> 2);
        unsigned int mk0 = bit_mask(W0, krl);
        float p0 = exp2v(s[hh][0][r]);
        s[hh][0][r] = __builtin_bit_cast(float, __builtin_bit_cast(unsigned int, p0) & mk0);
        unsigned int mk1 = bit_mask(W1, krl);
        float p1 = exp2v(s[hh][1][r]);
        s[hh][1][r] = __builtin_bit_cast(float, __builtin_bit_cast(unsigned int, p1) & mk1);
      }
#pragma unroll
      for (int kc = 0; kc < 4; ++kc) {
        const int rb = (kc & 1) * 8;
        const int st = kc >> 1;
        unsigned int w0 = cvtpk(s[hh][st][rb + 0], s[hh][st][rb + 1]);
        unsigned int w1 = cvtpk(s[hh][st][rb + 2], s[hh][st][rb + 3]);
        unsigned int w2 = cvtpk(s[hh][st][rb + 4], s[hh][st][rb + 5]);
        unsigned int w3 = cvtpk(s[hh][st][rb + 6], s[hh][st][rb + 7]);
        unsigned int u0, u1, u2, u3;
#if __has_builtin(__builtin_amdgcn_permlane32_swap)
        { auto r02 = __builtin_amdgcn_permlane32_swap(w0, w2, false, false);
          u0 = r02[0]; u2 = r02[1]; }
        { auto r13 = __builtin_amdgcn_permlane32_swap(w1, w3, false, false);
          u1 = r13[0]; u3 = r13[1]; }
#else
        { unsigned int t0 = (unsigned int)__shfl_xor((int)w0, 32);
          unsigned int t2 = (unsigned int)__shfl_xor((int)w2, 32);
          u0 = hi ? t2 : w0; u2 = hi ? w2 : t0;
          unsigned int t1 = (unsigned int)__shfl_xor((int)w1, 32);
          unsigned int t3 = (unsigned int)__shfl_xor((int)w3, 32);
          u1 = hi ? t3 : w1; u3 = hi ? w3 : t1; }
#endif
        pw[hh][kc] = u32x4{u0, u1, u2, u3};
      }
    }

    // ---- phase 5: PV MFMA cluster (24) ----
    __builtin_amdgcn_s_setprio(1);
#pragma unroll
    for (int hh = 0; hh < 2; ++hh)
#pragma unroll
      for (int kc = 0; kc < 4; ++kc) {
        bf16x8 pf = __builtin_bit_cast(bf16x8, pw[hh][kc]);
        o0 = __builtin_amdgcn_mfma_f32_32x32x16_bf16(vf[hh][0][kc], pf, o0, 0, 0, 0);
        o1 = __builtin_amdgcn_mfma_f32_32x32x16_bf16(vf[hh][1][kc], pf, o1, 0, 0, 0);
        o2 = __builtin_amdgcn_mfma_f32_32x32x16_bf16(onesf, pf, o2, 0, 0, 0);
      }
    __builtin_amdgcn_s_setprio(0);
  }

  // ---- epilogue: normalize (lsum = o2[0], identical in all lanes of col ql) ----
  float inv = 1.f / o2[0];
  unsigned short* Xp = X + ((size_t)b * S_ + q_g) * D_ + h * DK_;
#pragma unroll
  for (int rb = 0; rb < 4; ++rb) {
    int d0 = 8 * rb + 4 * hi;
    *(unsigned int*)(Xp + d0) = cvtpk(o0[4 * rb + 0] * inv, o0[4 * rb + 1] * inv);
    *(unsigned int*)(Xp + d0 + 2) = cvtpk(o0[4 * rb + 2] * inv, o0[4 * rb + 3] * inv);
    *(unsigned int*)(Xp + 32 + d0) = cvtpk(o1[4 * rb + 0] * inv, o1[4 * rb + 1] * inv);
    *(unsigned int*)(Xp + 32 + d0 + 2) = cvtpk(o1[4 * rb + 2] * inv, o1[4 * rb + 3] * inv);
  }
}

extern "C" void kernel_launch(void* const* d_in, const int* in_sizes, int n_in,
                              void* d_out, int out_size, void* d_ws, size_t ws_size,
                              hipStream_t stream) {
  const float* query = (const float*)d_in[0];
  const float* key = (const float*)d_in[1];
  const float* value = (const float*)d_in[2];
  const int* mask = (const int*)d_in[3];
  const float* Wq = (const float*)d_in[4];
  const float* bq = (const float*)d_in[5];
  const float* Wk = (const float*)d_in[6];
  const float* bk = (const float*)d_in[7];
  const float* Wv = (const float*)d_in[8];
  const float* bv = (const float*)d_in[9];
  const float* Wo = (const float*)d_in[10];
  const float* bo = (const float*)d_in[11];
  float* out = (float*)d_out;

  const size_t ACT = (size_t)B_ * S_ * D_;  // 4,194,304
  const size_t WSZ = (size_t)D_ * D_;
  unsigned short* ws = (unsigned short*)d_ws;
  unsigned short* xq = ws;                 // reused as xb (attn out) after qkv_gemm
  unsigned short* xk = xq + ACT;
  unsigned short* xv = xk + ACT;
  unsigned short* wtq = xv + ACT;
  unsigned short* wtk = wtq + WSZ;
  unsigned short* wtv = wtk + WSZ;
  unsigned short* wto = wtv + WSZ;
  unsigned short* qb = wto + WSZ;
  unsigned short* kb = qb + ACT;
  unsigned short* vt = kb + ACT;
  unsigned int* mbp = (unsigned int*)(vt + ACT);  // 1MB bit-packed mask
  unsigned short* xb = xq;                        // alias: xq dead after qkv_gemm

  prep_kernel<<<18432, 256, 0, stream>>>(query, key, value, xq, xk, xv,
                                         Wq, Wk, Wv, Wo, wtq, wtk, wtv, wto,
                                         mask, mbp);

  dim3 gg(8, 32, 3);   // 256 blocks/slice (32 m x 8 n), nwg multiple of 8 per slice
  qkv_gemm_kernel<<<gg, 256, 0, stream>>>(xq, xk, xv, wtq, wtk, wtv,
                                          bq, bk, bv, qb, kb, vt);

  dim3 ag(S_ / 128, B_ * H_);
  attn_kernel<<<ag, 256, 0, stream>>>(qb, kb, vt, mbp, xb);

  dim3 og(16, 32, 1);
  out_gemm_kernel<<<og, 256, 0, stream>>>(xb, wto, bo, out);
}

// Round 24
// 135.554 us; speedup vs baseline: 1.0866x; 1.0866x over previous
//
#include <hip/hip_runtime.h>
#include <cstdint>

#define B_ 2
#define S_ 2048
#define D_ 1024
#define H_ 16
#define DK_ 64
// 0.125 (1/sqrt(DK)) * log2(e): folded into Wq/bq so softmax uses exp2 directly
#define SCALE_ 0.18033688011112042f

typedef float f32x4 __attribute__((ext_vector_type(4)));
typedef float f32x16 __attribute__((ext_vector_type(16)));
typedef __bf16 bf16x8 __attribute__((ext_vector_type(8)));
typedef unsigned short u16x8 __attribute__((ext_vector_type(8)));
typedef unsigned short u16x4 __attribute__((ext_vector_type(4)));
typedef unsigned int u32x4 __attribute__((ext_vector_type(4)));

__device__ __forceinline__ unsigned short f2bf(float x) {
  unsigned int u = __builtin_bit_cast(unsigned int, x);
  u += 0x7FFFu + ((u >> 16) & 1u);   // round-to-nearest-even
  return (unsigned short)(u >> 16);
}

__device__ __forceinline__ void gload16(const void* g, void* l) {
  __builtin_amdgcn_global_load_lds((__attribute__((address_space(1))) void*)(void*)g,
                                   (__attribute__((address_space(3))) void*)l, 16, 0, 0);
}

__device__ __forceinline__ float exp2v(float x) {
  float r;
  asm("v_exp_f32 %0, %1" : "=v"(r) : "v"(x));
  return r;
}

__device__ __forceinline__ unsigned int cvtpk(float a, float b) {
  unsigned int r;
  asm("v_cvt_pk_bf16_f32 %0, %1, %2" : "=v"(r) : "v"(a), "v"(b));
  return r;
}

// sign-extended 1-bit field: 0 or 0xFFFFFFFF
__device__ __forceinline__ unsigned int bit_mask(unsigned int w, int bit) {
#if __has_builtin(__builtin_amdgcn_sbfe)
  return (unsigned int)__builtin_amdgcn_sbfe((int)w, bit, 1);
#else
  return (unsigned int)((int)(w << (31 - bit)) >> 31);
#endif
}

// ---------------- prep: wtrans | maskpack ----------------
// blocks [0,4096): weight transpose+convert. blocks [4096,12288): mask bit-pack,
// 1024 elements per block (4 waves x 4 strided ballots, 32B packed store per wave).
__global__ __launch_bounds__(256) void prep_kernel(
    const float* __restrict__ w0, const float* __restrict__ w1,
    const float* __restrict__ w2, const float* __restrict__ w3,
    unsigned short* o0, unsigned short* o1, unsigned short* o2, unsigned short* o3,
    const int* __restrict__ mask, unsigned int* __restrict__ mb) {
  __shared__ float t[32][33];
  const int bid = blockIdx.x;
  const int tid = threadIdx.x;
  if (bid < 4096) {
    const int z = bid >> 10, rr = bid & 1023;
    const float* W;
    unsigned short* O;
    float sc = 1.f;
    if (z == 0) { W = w0; O = o0; sc = SCALE_; }
    else if (z == 1) { W = w1; O = o1; }
    else if (z == 2) { W = w2; O = o2; }
    else { W = w3; O = o3; }
    const int n0 = (rr & 31) * 32, k0 = (rr >> 5) * 32;
    const int tx = tid & 31, ty = tid >> 5;
    for (int i = ty; i < 32; i += 8) t[i][tx] = W[(size_t)(k0 + i) * D_ + n0 + tx];
    __syncthreads();
    for (int i = ty; i < 32; i += 8) O[(size_t)(n0 + i) * D_ + k0 + tx] = f2bf(t[tx][i] * sc);
  } else {
    const int blk = bid - 4096;            // 0..8191
    const int w = tid >> 6, lane = tid & 63;
    const size_t base = ((size_t)blk * 4 + w) * 256;  // element base for this wave
    const int* mp = mask + base;
    // strided loads keep ballot bit order == element order within each 64-group
    unsigned long long b0 = __ballot(mp[lane] != 0);
    unsigned long long b1 = __ballot(mp[64 + lane] != 0);
    unsigned long long b2 = __ballot(mp[128 + lane] != 0);
    unsigned long long b3 = __ballot(mp[192 + lane] != 0);
    if (lane == 0) {
      unsigned long long* dst = (unsigned long long*)(mb + (base >> 5));
      dst[0] = b0; dst[1] = b1; dst[2] = b2; dst[3] = b3;
    }
  }
}

// ---------------- TMxTN bf16 GEMM, B transposed (BT[n][k]), bias add ----------------
// MODE: 0 = bf16 row-major out, 1 = f32 row-major out, 2 = bf16 transposed out to [B][D][S]
// AF32: A fp32 converted during reg-staging; A LDS 2-buffer, B LDS 3-buffer staged 2
//       tiles ahead. Barrier uses vmcnt(4): stageB(kt+2)+flats(kt+2) cross in flight;
//       stageB(kt+1) is retired mid-iteration by writeA's compiler wait on flats(kt+1).
// !AF32: gload_lds both operands; 3-buffer, staged 2 ahead (R20-proven).
// Waves: NWM x NWN = 4. LDS: AlS (2 or 3)*TM*32, BlS 3*TN*32 ushorts.
template <int MODE, int TM, int TN, int NWM, int NWN, bool AF32>
__device__ __forceinline__ void gemm_t(const void* __restrict__ Ap,
                                       const unsigned short* __restrict__ BT,
                                       const float* __restrict__ bias, float bsc,
                                       void* __restrict__ Cp,
                                       unsigned short* __restrict__ AlS,
                                       unsigned short* __restrict__ BlS,
                                       int M, int N, int K) {
  static_assert(NWM * NWN == 4, "4 waves");
  constexpr int WM = TM / NWM;    // rows per wave
  constexpr int WN = TN / NWN;    // cols per wave
  constexpr int MR = WM / 16, NR = WN / 16;
  constexpr int ASTRIDE = TM * 32;
  constexpr int BSTRIDE = TN * 32;
  const unsigned short* A16 = (const unsigned short*)Ap;
  const float* A32 = (const float*)Ap;
  const int tid = threadIdx.x;
  const int lane = tid & 63;
  const int w = tid >> 6;
  const int wr = w / NWN, wc = w % NWN;
  // XCD-chunked bijective remap (nwg must be a multiple of 8)
  const int nwg = gridDim.x * gridDim.y;
  const int wg = blockIdx.x + gridDim.x * blockIdx.y;
  const int work = (wg & 7) * (nwg >> 3) + (wg >> 3);
  const int nx = N / TN;
  const int m0 = (work / nx) * TM, n0 = (work % nx) * TN;

  f32x4 acc[MR][NR] = {};
  const int nk = K / 32;
  const int srow = lane >> 2;                              // staging row within 16-row chunk
  const int sxor = ((lane & 3) ^ ((srow >> 1) & 3)) * 8;   // swizzled seg (ushort offset)
  const int scol_lin = (lane & 3) * 8;                     // linear seg (f32 source)

  const int fr = lane & 15;
  const int rsw = ((lane >> 4) ^ ((fr >> 1) & 3)) * 8;     // read seg (swizzled), ushorts

  auto stageB = [&](int kt, int bufi) {
#pragma unroll
    for (int it = 0; it < TN / 64; ++it) {
      int chunk = it * 4 + w;
      gload16(BT + (size_t)(n0 + chunk * 16 + srow) * K + kt * 32 + sxor,
              BlS + bufi * BSTRIDE + chunk * 512);
    }
  };
  auto stageA16 = [&](int kt, int bufi) {
#pragma unroll
    for (int it = 0; it < TM / 64; ++it) {
      int chunk = it * 4 + w;
      gload16(A16 + (size_t)(m0 + chunk * 16 + srow) * K + kt * 32 + sxor,
              AlS + bufi * ASTRIDE + chunk * 512);
    }
  };

  auto loadA32 = [&](int kt, f32x4 (&aR)[TM / 64][2]) {
#pragma unroll
    for (int it = 0; it < TM / 64; ++it) {
      int chunk = it * 4 + w;
      const float* ga = A32 + (size_t)(m0 + chunk * 16 + srow) * K + kt * 32 + scol_lin;
      aR[it][0] = *(const f32x4*)ga;
      aR[it][1] = *(const f32x4*)(ga + 4);
    }
  };
  auto writeA = [&](int bufi, f32x4 (&aR)[TM / 64][2]) {
#pragma unroll
    for (int it = 0; it < TM / 64; ++it) {
      int chunk = it * 4 + w;
      u32x4 pk;
      pk[0] = cvtpk(aR[it][0][0], aR[it][0][1]);
      pk[1] = cvtpk(aR[it][0][2], aR[it][0][3]);
      pk[2] = cvtpk(aR[it][1][0], aR[it][1][1]);
      pk[3] = cvtpk(aR[it][1][2], aR[it][1][3]);
      *(u32x4*)(AlS + bufi * ASTRIDE + chunk * 512 + srow * 32 + sxor) = pk;
    }
  };
  auto compute = [&](int abuf, int bbuf) {
    bf16x8 af[MR], bf[NR];
#pragma unroll
    for (int i = 0; i < MR; ++i)
      af[i] = __builtin_bit_cast(bf16x8,
          *(const u16x8*)(AlS + abuf * ASTRIDE + (wr * WM + i * 16 + fr) * 32 + rsw));
#pragma unroll
    for (int j = 0; j < NR; ++j)
      bf[j] = __builtin_bit_cast(bf16x8,
          *(const u16x8*)(BlS + bbuf * BSTRIDE + (wc * WN + j * 16 + fr) * 32 + rsw));
    __builtin_amdgcn_s_setprio(1);
#pragma unroll
    for (int i = 0; i < MR; ++i)
#pragma unroll
      for (int j = 0; j < NR; ++j)
        acc[i][j] = __builtin_amdgcn_mfma_f32_16x16x32_bf16(af[i], bf[j], acc[i][j], 0, 0, 0);
    __builtin_amdgcn_s_setprio(0);
  };

  if (AF32) {
    // A: 2-buffer (ds_write), single reg set. B: 3-buffer gload_lds staged 2 ahead.
    f32x4 aA[TM / 64][2];
    loadA32(0, aA);
    writeA(0, aA);           // tile 0 -> A-buf 0 (drains flats(0) via compiler wait)
    stageB(0, 0);
    if (nk > 1) stageB(1, 1);
    if (nk > 1) loadA32(1, aA);
    // outstanding: B0[2] (oldest), B1[2], flats1[2] -> vmcnt(4) retires B0 only
    asm volatile("s_waitcnt vmcnt(4) lgkmcnt(0)" ::: "memory");
    __builtin_amdgcn_s_barrier();
    __builtin_amdgcn_sched_barrier(0);
    for (int kt = 0; kt < nk; ++kt) {
      if (kt + 2 < nk) stageB(kt + 2, (kt + 2) % 3);
      compute(kt & 1, kt % 3);
      if (kt + 1 < nk) writeA((kt + 1) & 1, aA);  // waits flats(kt+1) -> also retires B(kt+1)
      if (kt + 2 < nk) loadA32(kt + 2, aA);       // new flats in flight
      if (kt + 1 < nk) {
        // crossing loads: stageB(kt+2)[2] + flats(kt+2)[2]; nothing must retire here
        asm volatile("s_waitcnt vmcnt(4) lgkmcnt(0)" ::: "memory");
        __builtin_amdgcn_s_barrier();
        __builtin_amdgcn_sched_barrier(0);
      }
    }
  } else {
    // 3-buffer, 2-ahead counted-vmcnt pipeline: per stage = TM/64 + TN/64 loads.
    constexpr int SLOADS = TM / 64 + TN / 64;
    auto stage = [&](int kt, int bufi) { stageA16(kt, bufi); stageB(kt, bufi); };
    stage(0, 0);
    if (nk > 1) stage(1, 1);
    asm volatile("s_waitcnt vmcnt(%0) lgkmcnt(0)" :: "i"(SLOADS) : "memory");  // stage0 done
    __builtin_amdgcn_s_barrier();
    __builtin_amdgcn_sched_barrier(0);
    for (int kt = 0; kt < nk; ++kt) {
      if (kt + 2 < nk) stage(kt + 2, (kt + 2) % 3);  // buffer last read at iter kt-1
      compute(kt % 3, kt % 3);
      if (kt + 1 < nk) {
        if (kt + 2 < nk)
          asm volatile("s_waitcnt vmcnt(%0) lgkmcnt(0)" :: "i"(SLOADS) : "memory");
        else
          asm volatile("s_waitcnt vmcnt(0) lgkmcnt(0)" ::: "memory");
        __builtin_amdgcn_s_barrier();
        __builtin_amdgcn_sched_barrier(0);
      }
    }
  }

  const int rg = (lane >> 4) * 4;
  const int cg = lane & 15;
#pragma unroll
  for (int i = 0; i < MR; ++i)
#pragma unroll
    for (int j = 0; j < NR; ++j) {
      int col = n0 + wc * WN + j * 16 + cg;
      float bv = bias[col] * bsc;
#pragma unroll
      for (int e = 0; e < 4; ++e) {
        int row = m0 + wr * WM + i * 16 + rg + e;
        float v = acc[i][j][e] + bv;
        if (MODE == 1)
          ((float*)Cp)[(size_t)row * N + col] = v;
        else if (MODE == 0)
          ((unsigned short*)Cp)[(size_t)row * N + col] = f2bf(v);
        else
          ((unsigned short*)Cp)[((size_t)(row >> 11) * D_ + col) * S_ + (row & (S_ - 1))] = f2bf(v);
      }
    }
}

// qkv: 64x128 tiles (1536 blocks), 2x2 waves of 32x64; B 3-buffer 2-ahead, A flats pipelined
__global__ __launch_bounds__(256) void qkv_gemm_kernel(
    const float* __restrict__ query, const float* __restrict__ key,
    const float* __restrict__ value, const unsigned short* __restrict__ wtq,
    const unsigned short* __restrict__ wtk, const unsigned short* __restrict__ wtv,
    const float* __restrict__ bq, const float* __restrict__ bk, const float* __restrict__ bv,
    unsigned short* q, unsigned short* k, unsigned short* vt) {
  __shared__ alignas(16) unsigned short As[2 * 64 * 32];
  __shared__ alignas(16) unsigned short Bs[3 * 128 * 32];
  if (blockIdx.z == 0)
    gemm_t<0, 64, 128, 2, 2, true>(query, wtq, bq, SCALE_, (void*)q, As, Bs, B_ * S_, D_, D_);
  else if (blockIdx.z == 1)
    gemm_t<0, 64, 128, 2, 2, true>(key, wtk, bk, 1.f, (void*)k, As, Bs, B_ * S_, D_, D_);
  else
    gemm_t<2, 64, 128, 2, 2, true>(value, wtv, bv, 1.f, (void*)vt, As, Bs, B_ * S_, D_, D_);
}

// out: 128x64 tiles, 3-buffer 2-ahead counted-vmcnt pipeline (R20-proven)
__global__ __launch_bounds__(256) void out_gemm_kernel(const unsigned short* __restrict__ x,
                                                       const unsigned short* __restrict__ wto,
                                                       const float* __restrict__ bo,
                                                       float* __restrict__ out) {
  __shared__ alignas(16) unsigned short As[3 * 128 * 32];
  __shared__ alignas(16) unsigned short Bs[3 * 64 * 32];
  gemm_t<1, 128, 64, 4, 1, false>(x, wto, bo, 1.f, (void*)out, As, Bs, B_ * S_, D_, D_);
}

// ---------------- flash attention, swapped-QK^T 32x32, clustered phases (R10 proven) ----------------
// Q,K bf16 [B,S,D] (Q pre-scaled by SCALE_); Vt bf16 [B,D,S]; mb bit-packed mask.
// 4 waves x 32 q-rows = 128 q/block; KVBLK=128 staged; double-buffered 64KB LDS;
// per iteration: [16 K ds_reads][stage][16 QK MFMA][16 V ds_reads][softmax][24 PV MFMA].
__global__ __launch_bounds__(256, 2) void attn_kernel(const unsigned short* __restrict__ Q,
                                                      const unsigned short* __restrict__ K,
                                                      const unsigned short* __restrict__ Vt,
                                                      const unsigned int* __restrict__ mb,
                                                      unsigned short* __restrict__ X) {
  __shared__ unsigned short Kl[2][128 * 64];     // [kv 0..127][d], XOR-swizzled 16B chunks
  __shared__ unsigned short Vl[2][2][64 * 64];   // [half][d][kv 64], XOR-swizzled

  const int tid = threadIdx.x;
  const int lane = tid & 63;
  const int w = tid >> 6;
  const int ql = lane & 31;
  const int hi = lane >> 5;

  // XCD-bijective remap: 512 blocks = 8 XCDs x 64; each XCD owns 4 consecutive bh
  const int wg = blockIdx.x + gridDim.x * blockIdx.y;
  const int swz = (wg & 7) * 64 + (wg >> 3);
  const int qt = swz & 15;
  const int bh = swz >> 4;
  const int b = bh >> 4, h = bh & 15;
  const int q_g = qt * 128 + w * 32 + ql;

  const size_t qkbase = ((size_t)b * S_) * D_ + h * DK_;
  const size_t vtbase = ((size_t)b * D_ + h * DK_) * S_;

  bf16x8 qf[4];
  {
    const unsigned short* qp = Q + qkbase + (size_t)q_g * D_ + hi * 8;
#pragma unroll
    for (int c = 0; c < 4; ++c)
      qf[c] = __builtin_bit_cast(bf16x8, *(const u16x8*)(qp + c * 16));
  }

  const int lr = lane >> 3;
  const int seg = (lane & 7) ^ lr;
  const unsigned short* Ks = K + qkbase + (size_t)(w * 32 + lr) * D_ + seg * 8;
  const unsigned short* Vs = Vt + vtbase + (size_t)(w * 16 + lr) * S_ + seg * 8;

  auto stage = [&](int kt, int bufi) {  // kt indexes 128-row KV tiles
#pragma unroll
    for (int c = 0; c < 4; ++c)
      gload16(Ks + ((size_t)kt * 128 + c * 8) * D_, &Kl[bufi][(w * 32 + c * 8) * 64]);
#pragma unroll
    for (int c = 0; c < 4; ++c)
      gload16(Vs + (size_t)((c & 1) * 8) * S_ + kt * 128 + (c >> 1) * 64,
              &Vl[bufi][c >> 1][(w * 16 + (c & 1) * 8) * 64]);
  };

  const unsigned long long* mrow =
      (const unsigned long long*)mb + ((size_t)b * S_ + q_g) * 32;

  f32x16 o0 = {}, o1 = {};  // O^T accumulators, d-tiles 0 (d 0..31) and 1 (d 32..63)
  f32x16 o2 = {};           // ones-MFMA accumulator: every row = sum_k P (lsum)
  const int sw = (ql & 7) << 4;

  const unsigned int one2 = 0x3F803F80u;  // two bf16 1.0
  const bf16x8 onesf = __builtin_bit_cast(bf16x8, u32x4{one2, one2, one2, one2});

  stage(0, 0);
  const int NT = S_ / 128;
  unsigned long long M0n = mrow[0], M1n = mrow[1];

  for (int kt = 0; kt < NT; ++kt) {
    const int buf = kt & 1;
    __syncthreads();                  // drains stage(kt); prior reads of buf^1 done
    unsigned long long M0 = M0n, M1 = M1n;

    // ---- phase 1: ALL K-fragment ds_reads (latency paid once, pipelined) ----
    bf16x8 kf[2][2][4];  // [half][subtile][c]
#pragma unroll
    for (int hh = 0; hh < 2; ++hh) {
      const char* Kb = (const char*)&Kl[buf][hh * 64 * 64];
#pragma unroll
      for (int r = 0; r < 2; ++r)
#pragma unroll
        for (int c = 0; c < 4; ++c)
          kf[hh][r][c] = __builtin_bit_cast(
              bf16x8, *(const u16x8*)(Kb + (((r * 32 + ql) * 128 + c * 32 + hi * 16) ^ sw)));
    }
    if (kt < NT - 1) {
      stage(kt + 1, buf ^ 1);
      M0n = mrow[kt * 2 + 2];  // prefetch next tile's mask words (off softmax path)
      M1n = mrow[kt * 2 + 3];
    }

    // ---- phase 2: QK^T MFMA cluster (16) ----
    f32x16 s[2][2] = {};  // [half][subtile]
    __builtin_amdgcn_s_setprio(1);
#pragma unroll
    for (int hh = 0; hh < 2; ++hh)
#pragma unroll
      for (int c = 0; c < 4; ++c) {
        s[hh][0] = __builtin_amdgcn_mfma_f32_32x32x16_bf16(kf[hh][0][c], qf[c], s[hh][0], 0, 0, 0);
        s[hh][1] = __builtin_amdgcn_mfma_f32_32x32x16_bf16(kf[hh][1][c], qf[c], s[hh][1], 0, 0, 0);
      }
    __builtin_amdgcn_s_setprio(0);

    // ---- phase 3: ALL V-fragment ds_reads (latency hides under softmax VALU) ----
    bf16x8 vf[2][2][4];  // [half][d-subtile][kc]
#pragma unroll
    for (int hh = 0; hh < 2; ++hh) {
      const char* Vb = (const char*)&Vl[buf][hh][0];
#pragma unroll
      for (int nt = 0; nt < 2; ++nt)
#pragma unroll
        for (int kc = 0; kc < 4; ++kc)
          vf[hh][nt][kc] = __builtin_bit_cast(
              bf16x8, *(const u16x8*)(Vb + (((nt * 32 + ql) * 128 + kc * 32 + hi * 16) ^ sw)));
    }

    // ---- phase 4: softmax + pack per half ----
    u32x4 pw[2][4];
#pragma unroll
    for (int hh = 0; hh < 2; ++hh) {
      const unsigned long long M = hh ? M1 : M0;
      unsigned int W0 = (unsigned int)(M >> (hi * 4));
      unsigned int W1 = (unsigned int)(M >> (32 + hi * 4));
#pragma unroll
      for (int r = 0; r < 16; ++r) {
        const int krl = (r & 3) + 8 * (r >> 2);
        unsigned int mk0 = bit_mask(W0, krl);
        float p0 = exp2v(s[hh][0][r]);
        s[hh][0][r] = __builtin_bit_cast(float, __builtin_bit_cast(unsigned int, p0) & mk0);
        unsigned int mk1 = bit_mask(W1, krl);
        float p1 = exp2v(s[hh][1][r]);
        s[hh][1][r] = __builtin_bit_cast(float, __builtin_bit_cast(unsigned int, p1) & mk1);
      }
#pragma unroll
      for (int kc = 0; kc < 4; ++kc) {
        const int rb = (kc & 1) * 8;
        const int st = kc >> 1;
        unsigned int w0 = cvtpk(s[hh][st][rb + 0], s[hh][st][rb + 1]);
        unsigned int w1 = cvtpk(s[hh][st][rb + 2], s[hh][st][rb + 3]);
        unsigned int w2 = cvtpk(s[hh][st][rb + 4], s[hh][st][rb + 5]);
        unsigned int w3 = cvtpk(s[hh][st][rb + 6], s[hh][st][rb + 7]);
        unsigned int u0, u1, u2, u3;
#if __has_builtin(__builtin_amdgcn_permlane32_swap)
        { auto r02 = __builtin_amdgcn_permlane32_swap(w0, w2, false, false);
          u0 = r02[0]; u2 = r02[1]; }
        { auto r13 = __builtin_amdgcn_permlane32_swap(w1, w3, false, false);
          u1 = r13[0]; u3 = r13[1]; }
#else
        { unsigned int t0 = (unsigned int)__shfl_xor((int)w0, 32);
          unsigned int t2 = (unsigned int)__shfl_xor((int)w2, 32);
          u0 = hi ? t2 : w0; u2 = hi ? w2 : t0;
          unsigned int t1 = (unsigned int)__shfl_xor((int)w1, 32);
          unsigned int t3 = (unsigned int)__shfl_xor((int)w3, 32);
          u1 = hi ? t3 : w1; u3 = hi ? w3 : t1; }
#endif
        pw[hh][kc] = u32x4{u0, u1, u2, u3};
      }
    }

    // ---- phase 5: PV MFMA cluster (24) ----
    __builtin_amdgcn_s_setprio(1);
#pragma unroll
    for (int hh = 0; hh < 2; ++hh)
#pragma unroll
      for (int kc = 0; kc < 4; ++kc) {
        bf16x8 pf = __builtin_bit_cast(bf16x8, pw[hh][kc]);
        o0 = __builtin_amdgcn_mfma_f32_32x32x16_bf16(vf[hh][0][kc], pf, o0, 0, 0, 0);
        o1 = __builtin_amdgcn_mfma_f32_32x32x16_bf16(vf[hh][1][kc], pf, o1, 0, 0, 0);
        o2 = __builtin_amdgcn_mfma_f32_32x32x16_bf16(onesf, pf, o2, 0, 0, 0);
      }
    __builtin_amdgcn_s_setprio(0);
  }

  // ---- epilogue: normalize (lsum = o2[0], identical in all lanes of col ql) ----
  float inv = 1.f / o2[0];
  unsigned short* Xp = X + ((size_t)b * S_ + q_g) * D_ + h * DK_;
#pragma unroll
  for (int rb = 0; rb < 4; ++rb) {
    int d0 = 8 * rb + 4 * hi;
    *(unsigned int*)(Xp + d0) = cvtpk(o0[4 * rb + 0] * inv, o0[4 * rb + 1] * inv);
    *(unsigned int*)(Xp + d0 + 2) = cvtpk(o0[4 * rb + 2] * inv, o0[4 * rb + 3] * inv);
    *(unsigned int*)(Xp + 32 + d0) = cvtpk(o1[4 * rb + 0] * inv, o1[4 * rb + 1] * inv);
    *(unsigned int*)(Xp + 32 + d0 + 2) = cvtpk(o1[4 * rb + 2] * inv, o1[4 * rb + 3] * inv);
  }
}

extern "C" void kernel_launch(void* const* d_in, const int* in_sizes, int n_in,
                              void* d_out, int out_size, void* d_ws, size_t ws_size,
                              hipStream_t stream) {
  const float* query = (const float*)d_in[0];
  const float* key = (const float*)d_in[1];
  const float* value = (const float*)d_in[2];
  const int* mask = (const int*)d_in[3];
  const float* Wq = (const float*)d_in[4];
  const float* bq = (const float*)d_in[5];
  const float* Wk = (const float*)d_in[6];
  const float* bk = (const float*)d_in[7];
  const float* Wv = (const float*)d_in[8];
  const float* bv = (const float*)d_in[9];
  const float* Wo = (const float*)d_in[10];
  const float* bo = (const float*)d_in[11];
  float* out = (float*)d_out;

  const size_t ACT = (size_t)B_ * S_ * D_;  // 4,194,304
  const size_t WSZ = (size_t)D_ * D_;
  unsigned short* ws = (unsigned short*)d_ws;
  unsigned short* wtq = ws;
  unsigned short* wtk = wtq + WSZ;
  unsigned short* wtv = wtk + WSZ;
  unsigned short* wto = wtv + WSZ;
  unsigned short* qb = wto + WSZ;
  unsigned short* kb = qb + ACT;
  unsigned short* vt = kb + ACT;
  unsigned int* mbp = (unsigned int*)(vt + ACT);          // 1MB bit-packed mask
  unsigned short* xb = (unsigned short*)(mbp + (size_t)B_ * S_ * S_ / 32);

  prep_kernel<<<12288, 256, 0, stream>>>(Wq, Wk, Wv, Wo, wtq, wtk, wtv, wto, mask, mbp);

  dim3 gg(8, 64, 3);   // 512 blocks/slice (64 m x 8 n), x*y multiple of 8 for XCD remap
  qkv_gemm_kernel<<<gg, 256, 0, stream>>>(query, key, value, wtq, wtk, wtv,
                                          bq, bk, bv, qb, kb, vt);

  dim3 ag(S_ / 128, B_ * H_);
  attn_kernel<<<ag, 256, 0, stream>>>(qb, kb, vt, mbp, xb);

  dim3 og(16, 32, 1);
  out_gemm_kernel<<<og, 256, 0, stream>>>(xb, wto, bo, out);
}